// Round 13
// baseline (1289.286 us; speedup 1.0000x reference)
//
#include <hip/hip_runtime.h>

#define B 16
#define N 8192
#define S1 512
#define S2 128
#define K 64

// ---------------------------------------------------------------------------
// DPP max step: wm = max(wm, dpp_shift(wm)). Value-only.
// ---------------------------------------------------------------------------
template<int CTRL>
__device__ __forceinline__ float dpp_max_f32(float v) {
  unsigned o = (unsigned)__builtin_amdgcn_update_dpp(
      (int)__float_as_uint(v), (int)__float_as_uint(v), CTRL, 0xF, 0xF, false);
  return fmaxf(v, __uint_as_float(o));
}

__device__ __forceinline__ float wave_max_bcast(float v) {
  v = dpp_max_f32<0x111>(v);  // row_shr:1
  v = dpp_max_f32<0x112>(v);  // row_shr:2
  v = dpp_max_f32<0x114>(v);  // row_shr:4
  v = dpp_max_f32<0x118>(v);  // row_shr:8
  v = dpp_max_f32<0x142>(v);  // row_bcast:15
  v = dpp_max_f32<0x143>(v);  // row_bcast:31 -> lane 63 holds wave max
  return __uint_as_float((unsigned)__builtin_amdgcn_readlane(
      (int)__float_as_uint(v), 63));  // SGPR broadcast to all lanes
}

// ---------------------------------------------------------------------------
// FPS stage 1 (multi-wave), FROZEN at the proven R13 config (450us, VGPR 52).
// ---------------------------------------------------------------------------
template<int NT, int PT, int MAXP, int MAXN>
__device__ __forceinline__ void fps_body(
    const float* __restrict__ pts, float* __restrict__ out_xyz,
    float* __restrict__ out2, int out2_stride, int n, int npoint) {
  const int b = blockIdx.x;
  const int t = threadIdx.x;
  const int w = t >> 6;
  const float* base = pts + (size_t)b * n * 3;
  __shared__ unsigned long long cell[3][4];
  __shared__ float s_out[MAXP * 3];
  __shared__ float s_pts[MAXN * 3];
  if (t < 12) ((unsigned long long*)cell)[t] = 0ull;
  float px[PT], py[PT], pz[PT], mind[PT];
#pragma unroll
  for (int i = 0; i < PT; i++) {
    int p = t + i * NT;
    px[i] = base[p * 3 + 0];
    py[i] = base[p * 3 + 1];
    pz[i] = base[p * 3 + 2];
    mind[i] = 1e10f;
    s_pts[p * 3 + 0] = px[i];
    s_pts[p * 3 + 1] = py[i];
    s_pts[p * 3 + 2] = pz[i];
  }
  float cx = base[0], cy = base[1], cz = base[2];
  __syncthreads();
  for (int it = 0; it < npoint; it++) {
    if (t == 0) {
      s_out[it * 3 + 0] = cx; s_out[it * 3 + 1] = cy; s_out[it * 3 + 2] = cz;
    }
    float bv = -1.0f;
#pragma unroll
    for (int i = 0; i < PT; i++) {
      float dx = px[i] - cx, dy = py[i] - cy, dz = pz[i] - cz;
      float d = dx * dx;
      d = fmaf(dy, dy, d);
      d = fmaf(dz, dz, d);
      float md = fminf(mind[i], d);
      mind[i] = md;
      bv = fmaxf(bv, md);
    }
    float gm = wave_max_bcast(bv);
    if (bv == gm) {
      int bi = 0;
#pragma unroll
      for (int i = PT - 1; i >= 0; i--)
        if (mind[i] == bv) bi = i;  // downward sweep -> smallest i survives
      unsigned long long kk = ((unsigned long long)__float_as_uint(bv) << 32) |
                              (~(unsigned)(t + bi * NT));
      atomicMax(&cell[it % 3][w & 3], kk);
    }
    if (t < 4) cell[(it + 1) % 3][t] = 0ull;
    __syncthreads();
    unsigned long long k0 = cell[it % 3][0];
    unsigned long long k1 = cell[it % 3][1];
    unsigned long long k2 = cell[it % 3][2];
    unsigned long long k3 = cell[it % 3][3];
    unsigned long long wk = k0 > k1 ? k0 : k1;
    unsigned long long wk2 = k2 > k3 ? k2 : k3;
    if (wk2 > wk) wk = wk2;
    int ui = __builtin_amdgcn_readfirstlane((int)(~(unsigned)wk));
    const float* q = s_pts + ui * 3;
    cx = q[0]; cy = q[1]; cz = q[2];
  }
  for (int e = t; e < npoint * 3; e += NT)
    out_xyz[(size_t)b * npoint * 3 + e] = s_out[e];
  if (out2) {
    for (int e = t; e < npoint; e += NT) {
      float* o2 = out2 + ((size_t)b * npoint + e) * out2_stride;
      o2[0] = s_out[e * 3 + 0];
      o2[1] = s_out[e * 3 + 1];
      o2[2] = s_out[e * 3 + 2];
    }
  }
}

__global__ __launch_bounds__(1024) __attribute__((amdgpu_waves_per_eu(4, 4)))
void fps1_kernel(const float* __restrict__ pts, float* __restrict__ out_xyz,
                 float* __restrict__ out2, int out2_stride, int n, int npoint) {
  fps_body<1024, 8, 512, 8192>(pts, out_xyz, out2, out2_stride, n, npoint);
}

// ---------------------------------------------------------------------------
// FPS stage 2 — single wave, barrier-free (R16, verified).
// ---------------------------------------------------------------------------
template<int PT, int MAXP, int MAXN>
__global__ __launch_bounds__(64) __attribute__((amdgpu_waves_per_eu(1, 1)))
void fps_wave_kernel(const float* __restrict__ pts, float* __restrict__ out_xyz,
                     float* __restrict__ out2, int out2_stride, int n, int npoint) {
  const int b = blockIdx.x;
  const int t = threadIdx.x;
  const float* base = pts + (size_t)b * n * 3;
  __shared__ unsigned long long cell[2];
  __shared__ float s_out[MAXP * 3];
  __shared__ float s_pts[MAXN * 3];
  if (t < 2) cell[t] = 0ull;
  float px[PT], py[PT], pz[PT], mind[PT];
#pragma unroll
  for (int i = 0; i < PT; i++) {
    int p = t + i * 64;
    px[i] = base[p * 3 + 0];
    py[i] = base[p * 3 + 1];
    pz[i] = base[p * 3 + 2];
    mind[i] = 1e10f;
    s_pts[p * 3 + 0] = px[i];
    s_pts[p * 3 + 1] = py[i];
    s_pts[p * 3 + 2] = pz[i];
  }
  float cx = base[0], cy = base[1], cz = base[2];
  for (int it = 0; it < npoint; it++) {
    if (t == 0) {
      s_out[it * 3 + 0] = cx; s_out[it * 3 + 1] = cy; s_out[it * 3 + 2] = cz;
    }
    float bv = -1.0f;
#pragma unroll
    for (int i = 0; i < PT; i++) {
      float dx = px[i] - cx, dy = py[i] - cy, dz = pz[i] - cz;
      float d = dx * dx;
      d = fmaf(dy, dy, d);
      d = fmaf(dz, dz, d);
      float md = fminf(mind[i], d);
      mind[i] = md;
      bv = fmaxf(bv, md);
    }
    float gm = wave_max_bcast(bv);
    if (bv == gm) {
      int bi = 0;
#pragma unroll
      for (int i = PT - 1; i >= 0; i--)
        if (mind[i] == bv) bi = i;
      unsigned long long kk = ((unsigned long long)__float_as_uint(bv) << 32) |
                              (~(unsigned)(t + bi * 64));
      atomicMax(&cell[it & 1], kk);
    }
    __threadfence_block();
    unsigned long long wk = cell[it & 1];
    if (t == 0) cell[(it + 1) & 1] = 0ull;
    int ui = __builtin_amdgcn_readfirstlane((int)(~(unsigned)wk));
    const float* q = s_pts + ui * 3;
    cx = q[0]; cy = q[1]; cz = q[2];
  }
  for (int e = t; e < npoint * 3; e += 64)
    out_xyz[(size_t)b * npoint * 3 + e] = s_out[e];
  if (out2) {
    for (int e = t; e < npoint; e += 64) {
      float* o2 = out2 + ((size_t)b * npoint + e) * out2_stride;
      o2[0] = s_out[e * 3 + 0];
      o2[1] = s_out[e * 3 + 1];
      o2[2] = s_out[e * 3 + 2];
    }
  }
}

// ---------------------------------------------------------------------------
// Ball query: one wave per center; ballot-scan in index order, first K
// in-radius; tail filled with first hit (or n-1).
// ---------------------------------------------------------------------------
__global__ __launch_bounds__(256) void ballq_kernel(
    const float* __restrict__ pts, const float* __restrict__ ctr,
    int* __restrict__ idx, int n, int ns, int total, float r2) {
  int gid = blockIdx.x * blockDim.x + threadIdx.x;
  int wid = gid >> 6;
  int lane = threadIdx.x & 63;
  if (wid >= total) return;
  int b = wid / ns, s = wid - b * ns;
  const float* pb = pts + (size_t)b * n * 3;
  const float* c = ctr + ((size_t)b * ns + s) * 3;
  float cx = c[0], cy = c[1], cz = c[2];
  float sc = cx * cx + cy * cy + cz * cz;
  int* out = idx + ((size_t)b * ns + s) * K;
  int cnt = 0, first = n - 1;
  for (int base = 0; base < n && cnt < K; base += 64) {
    int p = base + lane;
    float x = pb[p * 3 + 0], y = pb[p * 3 + 1], z = pb[p * 3 + 2];
    float sp = x * x + y * y + z * z;
    float dot = cx * x + cy * y + cz * z;
    float d2 = sc + sp - 2.0f * dot;
    bool inr = d2 < r2;
    unsigned long long m = __ballot(inr);
    if (cnt == 0 && m != 0ull) first = base + __ffsll((long long)m) - 1;
    int pre = (int)__popcll(m & ((1ull << lane) - 1ull));
    if (inr && (cnt + pre) < K) out[cnt + pre] = p;
    cnt += (int)__popcll(m);
  }
  if (cnt > K) cnt = K;
  if (lane >= cnt) out[lane] = first;
}

// ---------------------------------------------------------------------------
// SA1 grouped MLP (R18 phase-2 k-split, verified: DS reads halved, 1:8
// read:fma; LDS ~19 KB -> 8 blocks/CU).
// ---------------------------------------------------------------------------
__global__ __launch_bounds__(256) void sa1_kernel(
    const float* __restrict__ xyz, const int* __restrict__ idx,
    const float* __restrict__ ctr, const float* __restrict__ W1a,
    const float* __restrict__ b1a, const float* __restrict__ W1b,
    const float* __restrict__ b1b, float* __restrict__ feat) {
  __shared__ float s_l[K][3];
  __shared__ float s_h[K][64];
  __shared__ float s_red[4][128];
  int blk = blockIdx.x;
  int b = blk >> 9, s = blk & 511;
  int tid = threadIdx.x;
  const int* gi = idx + ((size_t)b * S1 + s) * K;
  const float* c = ctr + ((size_t)b * S1 + s) * 3;
  float cx = c[0], cy = c[1], cz = c[2];
  if (tid < K) {
    int p = gi[tid];
    const float* q = xyz + ((size_t)b * N + p) * 3;
    s_l[tid][0] = q[0] - cx;
    s_l[tid][1] = q[1] - cy;
    s_l[tid][2] = q[2] - cz;
  }
  __syncthreads();
  for (int e = tid; e < K * 64; e += 256) {
    int k = e >> 6, o = e & 63;
    float v = b1a[o] + W1a[o * 3 + 0] * s_l[k][0] + W1a[o * 3 + 1] * s_l[k][1] +
              W1a[o * 3 + 2] * s_l[k][2];
    s_h[k][o] = fmaxf(v, 0.f);
  }
  __syncthreads();
  // phase 2: outputs (oa, oa+64), k-quarter [k0, k0+16)
  {
    int oa = tid & 63, kq = tid >> 6, k0 = kq * 16;
    const float4* wpa = (const float4*)(W1b + oa * 64);
    const float4* wpb = (const float4*)(W1b + (oa + 64) * 64);
    float ba = b1b[oa], bb = b1b[oa + 64];
    float acca[16], accb[16];
#pragma unroll
    for (int j = 0; j < 16; j++) { acca[j] = ba; accb[j] = bb; }
    for (int c4 = 0; c4 < 16; c4++) {
      float4 wa = wpa[c4];
      float4 wb = wpb[c4];
#pragma unroll
      for (int j = 0; j < 16; j++) {
        float4 h = *(const float4*)(&s_h[k0 + j][c4 * 4]);  // broadcast; feeds 8 fma
        acca[j] = fmaf(h.x, wa.x, acca[j]);
        acca[j] = fmaf(h.y, wa.y, acca[j]);
        acca[j] = fmaf(h.z, wa.z, acca[j]);
        acca[j] = fmaf(h.w, wa.w, acca[j]);
        accb[j] = fmaf(h.x, wb.x, accb[j]);
        accb[j] = fmaf(h.y, wb.y, accb[j]);
        accb[j] = fmaf(h.z, wb.z, accb[j]);
        accb[j] = fmaf(h.w, wb.w, accb[j]);
      }
    }
    float ma = -1e30f, mb = -1e30f;
#pragma unroll
    for (int j = 0; j < 16; j++) { ma = fmaxf(ma, acca[j]); mb = fmaxf(mb, accb[j]); }
    s_red[kq][oa] = ma;
    s_red[kq][oa + 64] = mb;
  }
  __syncthreads();
  if (tid < 128) {
    float m = fmaxf(fmaxf(s_red[0][tid], s_red[1][tid]),
                    fmaxf(s_red[2][tid], s_red[3][tid]));
    feat[((size_t)b * S1 + s) * 128 + tid] = fmaxf(m, 0.f);
  }
}

// ---------------------------------------------------------------------------
// SA2 grouped MLP. ROUND-19 (resubmit after infra failure): theory — sa2 was
// LDS-capped at 2 blocks/CU (s_g 33.8K + s_h 32.8K = ~68 KB) -> 2 waves/
// SIMD, so phase A's 131 serial scalar W2a loads/thread (~200cyc L2 each
// batch) sat exposed (same trap as R14's 1-wave fps). Fix: process k in TWO
// 32-chunks with s_h[32][128] (16.4 KB); interleave phase A/B per chunk.
// LDS ~51.5 KB -> 3 blocks/CU (+50% TLP); waves_per_eu(3,3) stops allocator
// squeeze. Exactness: per-(o,k) fma chains keep identical c4/xyzw order +
// bias start; k-coverage is a disjoint union over (chunk, half); max over k
// is order-free; s_h reuse guarded by a barrier before chunk-1 writes
// (the `if (ch) __syncthreads()` is uniform — ch is a uniform loop counter).
// Cost: W2a row read 2x (L2-hot).
// ---------------------------------------------------------------------------
__global__ __launch_bounds__(256) __attribute__((amdgpu_waves_per_eu(3, 3)))
void sa2_kernel(
    const float* __restrict__ xyz1, const float* __restrict__ feat1,
    const int* __restrict__ idx, const float* __restrict__ ctr,
    const float* __restrict__ W2a, const float* __restrict__ b2a,
    const float* __restrict__ W2b, const float* __restrict__ b2b,
    float* __restrict__ in3) {
  __shared__ int s_pi[K];
  __shared__ float s_g[K][132];   // 131 cols + pad; rows 16B-aligned
  __shared__ float s_h[32][128];  // half-k chunk
  __shared__ float s_red[256];
  int blk = blockIdx.x;
  int b = blk >> 7, s = blk & 127;
  int tid = threadIdx.x;
  const int* gi = idx + ((size_t)b * S2 + s) * K;
  const float* c = ctr + ((size_t)b * S2 + s) * 3;
  float cx = c[0], cy = c[1], cz = c[2];
  if (tid < K) {
    int p = gi[tid];
    s_pi[tid] = p;
    const float* q = xyz1 + ((size_t)b * S1 + p) * 3;
    s_g[tid][0] = q[0] - cx;
    s_g[tid][1] = q[1] - cy;
    s_g[tid][2] = q[2] - cz;
  }
  __syncthreads();
  for (int e = tid; e < K * 128; e += 256) {
    int k = e >> 7, f = e & 127;
    s_g[k][3 + f] = feat1[((size_t)b * S1 + s_pi[k]) * 128 + f];
  }
  __syncthreads();

  const int o = tid & 127, half = tid >> 7;
  const float* wr = W2a + o * 131;
  const float biasA = b2a[o];
  const float4* wpa = (const float4*)(W2b + o * 128);
  const float4* wpb = (const float4*)(W2b + (o + 128) * 128);
  const float bba = b2b[o], bbb = b2b[o + 128];
  float bmaxa = -1e30f, bmaxb = -1e30f;  // phase-B running max across chunks

  for (int ch = 0; ch < 2; ch++) {
    // ---- phase A (chunk ch): h[k][o] for k in [ch*32 + half*16, +16) ----
    {
      int k0 = ch * 32 + half * 16;
      float acc[16];
#pragma unroll
      for (int j = 0; j < 16; j++) acc[j] = biasA;
      for (int c4 = 0; c4 < 32; c4++) {
        float w0 = wr[c4 * 4 + 0], w1 = wr[c4 * 4 + 1];
        float w2 = wr[c4 * 4 + 2], w3 = wr[c4 * 4 + 3];
#pragma unroll
        for (int j = 0; j < 16; j++) {
          float4 g = *(const float4*)(&s_g[k0 + j][c4 * 4]);
          acc[j] = fmaf(g.x, w0, acc[j]);
          acc[j] = fmaf(g.y, w1, acc[j]);
          acc[j] = fmaf(g.z, w2, acc[j]);
          acc[j] = fmaf(g.w, w3, acc[j]);
        }
      }
      float w0 = wr[128], w1 = wr[129], w2 = wr[130];
#pragma unroll
      for (int j = 0; j < 16; j++) {
        acc[j] = fmaf(s_g[k0 + j][128], w0, acc[j]);
        acc[j] = fmaf(s_g[k0 + j][129], w1, acc[j]);
        acc[j] = fmaf(s_g[k0 + j][130], w2, acc[j]);
      }
      if (ch) __syncthreads();  // chunk-0 phase-B reads of s_h must finish
#pragma unroll
      for (int j = 0; j < 16; j++)
        s_h[half * 16 + j][o] = fmaxf(acc[j], 0.f);
    }
    __syncthreads();
    // ---- phase B (chunk ch): accumulate outputs (o, o+128) over local k ----
    {
      int lk0 = half * 16;
      float acca[16], accb[16];
#pragma unroll
      for (int j = 0; j < 16; j++) { acca[j] = bba; accb[j] = bbb; }
      for (int c4 = 0; c4 < 32; c4++) {
        float4 wa = wpa[c4];
        float4 wb = wpb[c4];
#pragma unroll
        for (int j = 0; j < 16; j++) {
          float4 h = *(const float4*)(&s_h[lk0 + j][c4 * 4]);  // broadcast
          acca[j] = fmaf(h.x, wa.x, acca[j]);
          acca[j] = fmaf(h.y, wa.y, acca[j]);
          acca[j] = fmaf(h.z, wa.z, acca[j]);
          acca[j] = fmaf(h.w, wa.w, acca[j]);
          accb[j] = fmaf(h.x, wb.x, accb[j]);
          accb[j] = fmaf(h.y, wb.y, accb[j]);
          accb[j] = fmaf(h.z, wb.z, accb[j]);
          accb[j] = fmaf(h.w, wb.w, accb[j]);
        }
      }
#pragma unroll
      for (int j = 0; j < 16; j++) {
        bmaxa = fmaxf(bmaxa, acca[j]);
        bmaxb = fmaxf(bmaxb, accb[j]);
      }
    }
  }
  // combine the two thread-halves (each covers 32 of the 64 k's)
  if (half == 1) { s_red[o] = bmaxa; s_red[o + 128] = bmaxb; }
  __syncthreads();
  if (half == 0) {
    bmaxa = fmaxf(bmaxa, s_red[o]);
    bmaxb = fmaxf(bmaxb, s_red[o + 128]);
    float* o3 = &in3[((size_t)b * S2 + s) * 259 + 3];
    o3[o] = fmaxf(bmaxa, 0.f);
    o3[o + 128] = fmaxf(bmaxb, 0.f);
  }
}

// ---------------------------------------------------------------------------
// Final MLP layer a: h3[b][s][o] = relu(W3a[o] . in3[b][s] + b3a[o]).
// ---------------------------------------------------------------------------
__global__ __launch_bounds__(256) void mlp3a_kernel(
    const float* __restrict__ in3, const float* __restrict__ W3a,
    const float* __restrict__ b3a, float* __restrict__ h3) {
  __shared__ float s_wt[64][65];
  __shared__ float s_a[64][64];
  int blk = blockIdx.x;
  int b = blk >> 4, r = blk & 15;
  int ot = r >> 1, sh = r & 1;
  int tid = threadIdx.x;
  int o = tid & 63, sq = tid >> 6;
  float acc[16];
  float bias = b3a[ot * 64 + o];
#pragma unroll
  for (int j = 0; j < 16; j++) acc[j] = bias;
  for (int ch = 0; ch < 5; ch++) {
    int cb = ch * 64;
    int len = (ch == 4) ? 3 : 64;
    for (int e = tid; e < 4096; e += 256) {
      int oo = e >> 6, cc = e & 63;
      if (cc < len) s_wt[cc][oo] = W3a[(size_t)(ot * 64 + oo) * 259 + cb + cc];
    }
    for (int e = tid; e < 4096; e += 256) {
      int ss = e >> 6, cc = e & 63;
      if (cc < len) s_a[ss][cc] = in3[((size_t)b * S2 + sh * 64 + ss) * 259 + cb + cc];
    }
    __syncthreads();
    for (int cc = 0; cc < len; cc++) {
      float wv = s_wt[cc][o];
#pragma unroll
      for (int j = 0; j < 16; j++)
        acc[j] = fmaf(wv, s_a[sq * 16 + j][cc], acc[j]);
    }
    __syncthreads();
  }
#pragma unroll
  for (int j = 0; j < 16; j++) {
    int s = sh * 64 + sq * 16 + j;
    h3[((size_t)b * S2 + s) * 512 + ot * 64 + o] = fmaxf(acc[j], 0.f);
  }
}

// ---------------------------------------------------------------------------
// Final MLP layer b + global max-pool over the 128 proposals.
// ---------------------------------------------------------------------------
__global__ __launch_bounds__(256) void mlp3b_kernel(
    const float* __restrict__ h3, const float* __restrict__ W3b,
    const float* __restrict__ b3b, float* __restrict__ out) {
  __shared__ float s_wt[64][65];
  __shared__ float s_h[128][64];
  __shared__ float s_red[4][64];
  int blk = blockIdx.x;
  int b = blk >> 4, ot = blk & 15;
  int tid = threadIdx.x;
  int o = tid & 63, sq = tid >> 6;
  float acc[32];
  float bias = b3b[ot * 64 + o];
#pragma unroll
  for (int j = 0; j < 32; j++) acc[j] = bias;
  for (int ch = 0; ch < 8; ch++) {
    int cb = ch * 64;
    for (int e = tid; e < 4096; e += 256) {
      int oo = e >> 6, cc = e & 63;
      s_wt[cc][oo] = W3b[(size_t)(ot * 64 + oo) * 512 + cb + cc];
    }
    for (int e = tid; e < 8192; e += 256) {
      int ss = e >> 6, cc = e & 63;
      s_h[ss][cc] = h3[((size_t)b * S2 + ss) * 512 + cb + cc];
    }
    __syncthreads();
    for (int c4 = 0; c4 < 16; c4++) {
      float w0 = s_wt[c4 * 4 + 0][o];
      float w1 = s_wt[c4 * 4 + 1][o];
      float w2 = s_wt[c4 * 4 + 2][o];
      float w3 = s_wt[c4 * 4 + 3][o];
#pragma unroll
      for (int j = 0; j < 32; j++) {
        float4 h = *(const float4*)(&s_h[sq * 32 + j][c4 * 4]);
        acc[j] = fmaf(h.x, w0, acc[j]);
        acc[j] = fmaf(h.y, w1, acc[j]);
        acc[j] = fmaf(h.z, w2, acc[j]);
        acc[j] = fmaf(h.w, w3, acc[j]);
      }
    }
    __syncthreads();
  }
  float m = -1e30f;
#pragma unroll
  for (int j = 0; j < 32; j++) m = fmaxf(m, acc[j]);
  s_red[sq][o] = m;
  __syncthreads();
  if (sq == 0) {
    m = fmaxf(fmaxf(s_red[0][o], s_red[1][o]), fmaxf(s_red[2][o], s_red[3][o]));
    out[(size_t)b * 1024 + ot * 64 + o] = fmaxf(m, 0.f);
  }
}

extern "C" void kernel_launch(void* const* d_in, const int* in_sizes, int n_in,
                              void* d_out, int out_size, void* d_ws, size_t ws_size,
                              hipStream_t stream) {
  const float* x = (const float*)d_in[0];
  const float* W1a = (const float*)d_in[1];
  const float* b1a = (const float*)d_in[2];
  const float* W1b = (const float*)d_in[3];
  const float* b1b = (const float*)d_in[4];
  const float* W2a = (const float*)d_in[5];
  const float* b2a = (const float*)d_in[6];
  const float* W2b = (const float*)d_in[7];
  const float* b2b = (const float*)d_in[8];
  const float* W3a = (const float*)d_in[9];
  const float* b3a = (const float*)d_in[10];
  const float* W3b = (const float*)d_in[11];
  const float* b3b = (const float*)d_in[12];
  float* out = (float*)d_out;

  // workspace carve (floats/ints; all segments 16B-aligned) — ~13.3 MB total
  float* nx1 = (float*)d_ws;                       // [16,512,3]
  int* idx1 = (int*)(nx1 + 16 * 512 * 3);          // [16,512,64]
  float* feat1 = (float*)(idx1 + 16 * 512 * 64);   // [16,512,128]
  float* nx2 = feat1 + 16 * 512 * 128;             // [16,128,3]
  int* idx2 = (int*)(nx2 + 16 * 128 * 3);          // [16,128,64]
  float* in3 = (float*)(idx2 + 16 * 128 * 64);     // [16,128,259] = [xyz2|feat2]
  float* h3 = in3 + 16 * 128 * 259;                // [16,128,512]

  fps1_kernel<<<B, 1024, 0, stream>>>(x, nx1, nullptr, 0, N, S1);
  ballq_kernel<<<(B * S1) / 4, 256, 0, stream>>>(x, nx1, idx1, N, S1, B * S1, 0.04f);
  sa1_kernel<<<B * S1, 256, 0, stream>>>(x, idx1, nx1, W1a, b1a, W1b, b1b, feat1);
  fps_wave_kernel<8, 128, 512><<<B, 64, 0, stream>>>(nx1, nx2, in3, 259, S1, S2);
  ballq_kernel<<<(B * S2) / 4, 256, 0, stream>>>(nx1, nx2, idx2, S1, S2, B * S2, 0.16f);
  sa2_kernel<<<B * S2, 256, 0, stream>>>(nx1, feat1, idx2, nx2, W2a, b2a, W2b, b2b, in3);
  mlp3a_kernel<<<256, 256, 0, stream>>>(in3, W3a, b3a, h3);
  mlp3b_kernel<<<256, 256, 0, stream>>>(h3, W3b, b3b, out);
}

// Round 14
// 1201.933 us; speedup vs baseline: 1.0727x; 1.0727x over previous
//
#include <hip/hip_runtime.h>

#define B 16
#define N 8192
#define S1 512
#define S2 128
#define K 64

// ---------------------------------------------------------------------------
// DPP max step: wm = max(wm, dpp_shift(wm)). Value-only.
// ---------------------------------------------------------------------------
template<int CTRL>
__device__ __forceinline__ float dpp_max_f32(float v) {
  unsigned o = (unsigned)__builtin_amdgcn_update_dpp(
      (int)__float_as_uint(v), (int)__float_as_uint(v), CTRL, 0xF, 0xF, false);
  return fmaxf(v, __uint_as_float(o));
}

__device__ __forceinline__ float wave_max_bcast(float v) {
  v = dpp_max_f32<0x111>(v);  // row_shr:1
  v = dpp_max_f32<0x112>(v);  // row_shr:2
  v = dpp_max_f32<0x114>(v);  // row_shr:4
  v = dpp_max_f32<0x118>(v);  // row_shr:8
  v = dpp_max_f32<0x142>(v);  // row_bcast:15
  v = dpp_max_f32<0x143>(v);  // row_bcast:31 -> lane 63 holds wave max
  return __uint_as_float((unsigned)__builtin_amdgcn_readlane(
      (int)__float_as_uint(v), 63));  // SGPR broadcast to all lanes
}

// ---------------------------------------------------------------------------
// FPS stage 1 (multi-wave), FROZEN at the proven R13-config (448us, VGPR 52).
// ROUND-20: R13's sa2 chunking FALSIFIED (1289 vs R11's 1212; pre-commit
// threshold 1190 fired) — this file reverts sa2 to the R11 version so the
// session ends on the best harness-verified configuration (1212us).
// ---------------------------------------------------------------------------
template<int NT, int PT, int MAXP, int MAXN>
__device__ __forceinline__ void fps_body(
    const float* __restrict__ pts, float* __restrict__ out_xyz,
    float* __restrict__ out2, int out2_stride, int n, int npoint) {
  const int b = blockIdx.x;
  const int t = threadIdx.x;
  const int w = t >> 6;
  const float* base = pts + (size_t)b * n * 3;
  __shared__ unsigned long long cell[3][4];
  __shared__ float s_out[MAXP * 3];
  __shared__ float s_pts[MAXN * 3];
  if (t < 12) ((unsigned long long*)cell)[t] = 0ull;
  float px[PT], py[PT], pz[PT], mind[PT];
#pragma unroll
  for (int i = 0; i < PT; i++) {
    int p = t + i * NT;
    px[i] = base[p * 3 + 0];
    py[i] = base[p * 3 + 1];
    pz[i] = base[p * 3 + 2];
    mind[i] = 1e10f;
    s_pts[p * 3 + 0] = px[i];
    s_pts[p * 3 + 1] = py[i];
    s_pts[p * 3 + 2] = pz[i];
  }
  float cx = base[0], cy = base[1], cz = base[2];
  __syncthreads();
  for (int it = 0; it < npoint; it++) {
    if (t == 0) {
      s_out[it * 3 + 0] = cx; s_out[it * 3 + 1] = cy; s_out[it * 3 + 2] = cz;
    }
    float bv = -1.0f;
#pragma unroll
    for (int i = 0; i < PT; i++) {
      float dx = px[i] - cx, dy = py[i] - cy, dz = pz[i] - cz;
      float d = dx * dx;
      d = fmaf(dy, dy, d);
      d = fmaf(dz, dz, d);
      float md = fminf(mind[i], d);
      mind[i] = md;
      bv = fmaxf(bv, md);
    }
    float gm = wave_max_bcast(bv);
    if (bv == gm) {
      int bi = 0;
#pragma unroll
      for (int i = PT - 1; i >= 0; i--)
        if (mind[i] == bv) bi = i;  // downward sweep -> smallest i survives
      unsigned long long kk = ((unsigned long long)__float_as_uint(bv) << 32) |
                              (~(unsigned)(t + bi * NT));
      atomicMax(&cell[it % 3][w & 3], kk);
    }
    if (t < 4) cell[(it + 1) % 3][t] = 0ull;
    __syncthreads();
    unsigned long long k0 = cell[it % 3][0];
    unsigned long long k1 = cell[it % 3][1];
    unsigned long long k2 = cell[it % 3][2];
    unsigned long long k3 = cell[it % 3][3];
    unsigned long long wk = k0 > k1 ? k0 : k1;
    unsigned long long wk2 = k2 > k3 ? k2 : k3;
    if (wk2 > wk) wk = wk2;
    int ui = __builtin_amdgcn_readfirstlane((int)(~(unsigned)wk));
    const float* q = s_pts + ui * 3;
    cx = q[0]; cy = q[1]; cz = q[2];
  }
  for (int e = t; e < npoint * 3; e += NT)
    out_xyz[(size_t)b * npoint * 3 + e] = s_out[e];
  if (out2) {
    for (int e = t; e < npoint; e += NT) {
      float* o2 = out2 + ((size_t)b * npoint + e) * out2_stride;
      o2[0] = s_out[e * 3 + 0];
      o2[1] = s_out[e * 3 + 1];
      o2[2] = s_out[e * 3 + 2];
    }
  }
}

__global__ __launch_bounds__(1024) __attribute__((amdgpu_waves_per_eu(4, 4)))
void fps1_kernel(const float* __restrict__ pts, float* __restrict__ out_xyz,
                 float* __restrict__ out2, int out2_stride, int n, int npoint) {
  fps_body<1024, 8, 512, 8192>(pts, out_xyz, out2, out2_stride, n, npoint);
}

// ---------------------------------------------------------------------------
// FPS stage 2 — single wave, barrier-free (R16, verified).
// ---------------------------------------------------------------------------
template<int PT, int MAXP, int MAXN>
__global__ __launch_bounds__(64) __attribute__((amdgpu_waves_per_eu(1, 1)))
void fps_wave_kernel(const float* __restrict__ pts, float* __restrict__ out_xyz,
                     float* __restrict__ out2, int out2_stride, int n, int npoint) {
  const int b = blockIdx.x;
  const int t = threadIdx.x;
  const float* base = pts + (size_t)b * n * 3;
  __shared__ unsigned long long cell[2];
  __shared__ float s_out[MAXP * 3];
  __shared__ float s_pts[MAXN * 3];
  if (t < 2) cell[t] = 0ull;
  float px[PT], py[PT], pz[PT], mind[PT];
#pragma unroll
  for (int i = 0; i < PT; i++) {
    int p = t + i * 64;
    px[i] = base[p * 3 + 0];
    py[i] = base[p * 3 + 1];
    pz[i] = base[p * 3 + 2];
    mind[i] = 1e10f;
    s_pts[p * 3 + 0] = px[i];
    s_pts[p * 3 + 1] = py[i];
    s_pts[p * 3 + 2] = pz[i];
  }
  float cx = base[0], cy = base[1], cz = base[2];
  for (int it = 0; it < npoint; it++) {
    if (t == 0) {
      s_out[it * 3 + 0] = cx; s_out[it * 3 + 1] = cy; s_out[it * 3 + 2] = cz;
    }
    float bv = -1.0f;
#pragma unroll
    for (int i = 0; i < PT; i++) {
      float dx = px[i] - cx, dy = py[i] - cy, dz = pz[i] - cz;
      float d = dx * dx;
      d = fmaf(dy, dy, d);
      d = fmaf(dz, dz, d);
      float md = fminf(mind[i], d);
      mind[i] = md;
      bv = fmaxf(bv, md);
    }
    float gm = wave_max_bcast(bv);
    if (bv == gm) {
      int bi = 0;
#pragma unroll
      for (int i = PT - 1; i >= 0; i--)
        if (mind[i] == bv) bi = i;
      unsigned long long kk = ((unsigned long long)__float_as_uint(bv) << 32) |
                              (~(unsigned)(t + bi * 64));
      atomicMax(&cell[it & 1], kk);
    }
    __threadfence_block();
    unsigned long long wk = cell[it & 1];
    if (t == 0) cell[(it + 1) & 1] = 0ull;
    int ui = __builtin_amdgcn_readfirstlane((int)(~(unsigned)wk));
    const float* q = s_pts + ui * 3;
    cx = q[0]; cy = q[1]; cz = q[2];
  }
  for (int e = t; e < npoint * 3; e += 64)
    out_xyz[(size_t)b * npoint * 3 + e] = s_out[e];
  if (out2) {
    for (int e = t; e < npoint; e += 64) {
      float* o2 = out2 + ((size_t)b * npoint + e) * out2_stride;
      o2[0] = s_out[e * 3 + 0];
      o2[1] = s_out[e * 3 + 1];
      o2[2] = s_out[e * 3 + 2];
    }
  }
}

// ---------------------------------------------------------------------------
// Ball query: one wave per center; ballot-scan in index order, first K
// in-radius; tail filled with first hit (or n-1).
// ---------------------------------------------------------------------------
__global__ __launch_bounds__(256) void ballq_kernel(
    const float* __restrict__ pts, const float* __restrict__ ctr,
    int* __restrict__ idx, int n, int ns, int total, float r2) {
  int gid = blockIdx.x * blockDim.x + threadIdx.x;
  int wid = gid >> 6;
  int lane = threadIdx.x & 63;
  if (wid >= total) return;
  int b = wid / ns, s = wid - b * ns;
  const float* pb = pts + (size_t)b * n * 3;
  const float* c = ctr + ((size_t)b * ns + s) * 3;
  float cx = c[0], cy = c[1], cz = c[2];
  float sc = cx * cx + cy * cy + cz * cz;
  int* out = idx + ((size_t)b * ns + s) * K;
  int cnt = 0, first = n - 1;
  for (int base = 0; base < n && cnt < K; base += 64) {
    int p = base + lane;
    float x = pb[p * 3 + 0], y = pb[p * 3 + 1], z = pb[p * 3 + 2];
    float sp = x * x + y * y + z * z;
    float dot = cx * x + cy * y + cz * z;
    float d2 = sc + sp - 2.0f * dot;
    bool inr = d2 < r2;
    unsigned long long m = __ballot(inr);
    if (cnt == 0 && m != 0ull) first = base + __ffsll((long long)m) - 1;
    int pre = (int)__popcll(m & ((1ull << lane) - 1ull));
    if (inr && (cnt + pre) < K) out[cnt + pre] = p;
    cnt += (int)__popcll(m);
  }
  if (cnt > K) cnt = K;
  if (lane >= cnt) out[lane] = first;
}

// ---------------------------------------------------------------------------
// SA1 grouped MLP (R18 phase-2 k-split, verified: DS reads halved, 1:8
// read:fma; LDS ~19 KB -> 8 blocks/CU).
// ---------------------------------------------------------------------------
__global__ __launch_bounds__(256) void sa1_kernel(
    const float* __restrict__ xyz, const int* __restrict__ idx,
    const float* __restrict__ ctr, const float* __restrict__ W1a,
    const float* __restrict__ b1a, const float* __restrict__ W1b,
    const float* __restrict__ b1b, float* __restrict__ feat) {
  __shared__ float s_l[K][3];
  __shared__ float s_h[K][64];
  __shared__ float s_red[4][128];
  int blk = blockIdx.x;
  int b = blk >> 9, s = blk & 511;
  int tid = threadIdx.x;
  const int* gi = idx + ((size_t)b * S1 + s) * K;
  const float* c = ctr + ((size_t)b * S1 + s) * 3;
  float cx = c[0], cy = c[1], cz = c[2];
  if (tid < K) {
    int p = gi[tid];
    const float* q = xyz + ((size_t)b * N + p) * 3;
    s_l[tid][0] = q[0] - cx;
    s_l[tid][1] = q[1] - cy;
    s_l[tid][2] = q[2] - cz;
  }
  __syncthreads();
  for (int e = tid; e < K * 64; e += 256) {
    int k = e >> 6, o = e & 63;
    float v = b1a[o] + W1a[o * 3 + 0] * s_l[k][0] + W1a[o * 3 + 1] * s_l[k][1] +
              W1a[o * 3 + 2] * s_l[k][2];
    s_h[k][o] = fmaxf(v, 0.f);
  }
  __syncthreads();
  // phase 2: outputs (oa, oa+64), k-quarter [k0, k0+16)
  {
    int oa = tid & 63, kq = tid >> 6, k0 = kq * 16;
    const float4* wpa = (const float4*)(W1b + oa * 64);
    const float4* wpb = (const float4*)(W1b + (oa + 64) * 64);
    float ba = b1b[oa], bb = b1b[oa + 64];
    float acca[16], accb[16];
#pragma unroll
    for (int j = 0; j < 16; j++) { acca[j] = ba; accb[j] = bb; }
    for (int c4 = 0; c4 < 16; c4++) {
      float4 wa = wpa[c4];
      float4 wb = wpb[c4];
#pragma unroll
      for (int j = 0; j < 16; j++) {
        float4 h = *(const float4*)(&s_h[k0 + j][c4 * 4]);  // broadcast; feeds 8 fma
        acca[j] = fmaf(h.x, wa.x, acca[j]);
        acca[j] = fmaf(h.y, wa.y, acca[j]);
        acca[j] = fmaf(h.z, wa.z, acca[j]);
        acca[j] = fmaf(h.w, wa.w, acca[j]);
        accb[j] = fmaf(h.x, wb.x, accb[j]);
        accb[j] = fmaf(h.y, wb.y, accb[j]);
        accb[j] = fmaf(h.z, wb.z, accb[j]);
        accb[j] = fmaf(h.w, wb.w, accb[j]);
      }
    }
    float ma = -1e30f, mb = -1e30f;
#pragma unroll
    for (int j = 0; j < 16; j++) { ma = fmaxf(ma, acca[j]); mb = fmaxf(mb, accb[j]); }
    s_red[kq][oa] = ma;
    s_red[kq][oa + 64] = mb;
  }
  __syncthreads();
  if (tid < 128) {
    float m = fmaxf(fmaxf(s_red[0][tid], s_red[1][tid]),
                    fmaxf(s_red[2][tid], s_red[3][tid]));
    feat[((size_t)b * S1 + s) * 128 + tid] = fmaxf(m, 0.f);
  }
}

// ---------------------------------------------------------------------------
// SA2 grouped MLP (R11 version RESTORED — best verified config, 1212us
// total). Phase A full-k (s_h[K][128]); phase B k-split, 2 outputs/thread,
// h-reads shared (1:8 read:fma). R13's chunked variant was falsified.
// ---------------------------------------------------------------------------
__global__ __launch_bounds__(256) void sa2_kernel(
    const float* __restrict__ xyz1, const float* __restrict__ feat1,
    const int* __restrict__ idx, const float* __restrict__ ctr,
    const float* __restrict__ W2a, const float* __restrict__ b2a,
    const float* __restrict__ W2b, const float* __restrict__ b2b,
    float* __restrict__ in3) {
  __shared__ int s_pi[K];
  __shared__ float s_g[K][132];
  __shared__ float s_h[K][128];
  __shared__ float s_red[256];
  int blk = blockIdx.x;
  int b = blk >> 7, s = blk & 127;
  int tid = threadIdx.x;
  const int* gi = idx + ((size_t)b * S2 + s) * K;
  const float* c = ctr + ((size_t)b * S2 + s) * 3;
  float cx = c[0], cy = c[1], cz = c[2];
  if (tid < K) {
    int p = gi[tid];
    s_pi[tid] = p;
    const float* q = xyz1 + ((size_t)b * S1 + p) * 3;
    s_g[tid][0] = q[0] - cx;
    s_g[tid][1] = q[1] - cy;
    s_g[tid][2] = q[2] - cz;
  }
  __syncthreads();
  for (int e = tid; e < K * 128; e += 256) {
    int k = e >> 7, f = e & 127;
    s_g[k][3 + f] = feat1[((size_t)b * S1 + s_pi[k]) * 128 + f];
  }
  __syncthreads();
  // phase A
  {
    int o = tid & 127, half = tid >> 7, k0 = half * 32;
    const float* wr = W2a + o * 131;
    float acc[32];
    float bias = b2a[o];
#pragma unroll
    for (int j = 0; j < 32; j++) acc[j] = bias;
    for (int c4 = 0; c4 < 32; c4++) {
      float w0 = wr[c4 * 4 + 0], w1 = wr[c4 * 4 + 1];
      float w2 = wr[c4 * 4 + 2], w3 = wr[c4 * 4 + 3];
#pragma unroll
      for (int j = 0; j < 32; j++) {
        float4 g = *(const float4*)(&s_g[k0 + j][c4 * 4]);
        acc[j] = fmaf(g.x, w0, acc[j]);
        acc[j] = fmaf(g.y, w1, acc[j]);
        acc[j] = fmaf(g.z, w2, acc[j]);
        acc[j] = fmaf(g.w, w3, acc[j]);
      }
    }
    float w0 = wr[128], w1 = wr[129], w2 = wr[130];
#pragma unroll
    for (int j = 0; j < 32; j++) {
      acc[j] = fmaf(s_g[k0 + j][128], w0, acc[j]);
      acc[j] = fmaf(s_g[k0 + j][129], w1, acc[j]);
      acc[j] = fmaf(s_g[k0 + j][130], w2, acc[j]);
      s_h[k0 + j][o] = fmaxf(acc[j], 0.f);
    }
  }
  __syncthreads();
  // phase B (k-split, 2 outputs/thread)
  {
    int oa = tid & 127, half = tid >> 7, k0 = half * 32;
    const float4* wpa = (const float4*)(W2b + oa * 128);
    const float4* wpb = (const float4*)(W2b + (oa + 128) * 128);
    float acca[32], accb[32];
    float ba = b2b[oa], bb = b2b[oa + 128];
#pragma unroll
    for (int j = 0; j < 32; j++) { acca[j] = ba; accb[j] = bb; }
    for (int c4 = 0; c4 < 32; c4++) {
      float4 wa = wpa[c4];
      float4 wb = wpb[c4];
#pragma unroll
      for (int j = 0; j < 32; j++) {
        float4 h = *(const float4*)(&s_h[k0 + j][c4 * 4]);
        acca[j] = fmaf(h.x, wa.x, acca[j]);
        acca[j] = fmaf(h.y, wa.y, acca[j]);
        acca[j] = fmaf(h.z, wa.z, acca[j]);
        acca[j] = fmaf(h.w, wa.w, acca[j]);
        accb[j] = fmaf(h.x, wb.x, accb[j]);
        accb[j] = fmaf(h.y, wb.y, accb[j]);
        accb[j] = fmaf(h.z, wb.z, accb[j]);
        accb[j] = fmaf(h.w, wb.w, accb[j]);
      }
    }
    float ma = -1e30f, mb = -1e30f;
#pragma unroll
    for (int j = 0; j < 32; j++) { ma = fmaxf(ma, acca[j]); mb = fmaxf(mb, accb[j]); }
    if (half == 1) { s_red[oa] = ma; s_red[oa + 128] = mb; }
    __syncthreads();
    if (half == 0) {
      ma = fmaxf(ma, s_red[oa]);
      mb = fmaxf(mb, s_red[oa + 128]);
      float* o3 = &in3[((size_t)b * S2 + s) * 259 + 3];
      o3[oa] = fmaxf(ma, 0.f);
      o3[oa + 128] = fmaxf(mb, 0.f);
    }
  }
}

// ---------------------------------------------------------------------------
// Final MLP layer a: h3[b][s][o] = relu(W3a[o] . in3[b][s] + b3a[o]).
// ---------------------------------------------------------------------------
__global__ __launch_bounds__(256) void mlp3a_kernel(
    const float* __restrict__ in3, const float* __restrict__ W3a,
    const float* __restrict__ b3a, float* __restrict__ h3) {
  __shared__ float s_wt[64][65];
  __shared__ float s_a[64][64];
  int blk = blockIdx.x;
  int b = blk >> 4, r = blk & 15;
  int ot = r >> 1, sh = r & 1;
  int tid = threadIdx.x;
  int o = tid & 63, sq = tid >> 6;
  float acc[16];
  float bias = b3a[ot * 64 + o];
#pragma unroll
  for (int j = 0; j < 16; j++) acc[j] = bias;
  for (int ch = 0; ch < 5; ch++) {
    int cb = ch * 64;
    int len = (ch == 4) ? 3 : 64;
    for (int e = tid; e < 4096; e += 256) {
      int oo = e >> 6, cc = e & 63;
      if (cc < len) s_wt[cc][oo] = W3a[(size_t)(ot * 64 + oo) * 259 + cb + cc];
    }
    for (int e = tid; e < 4096; e += 256) {
      int ss = e >> 6, cc = e & 63;
      if (cc < len) s_a[ss][cc] = in3[((size_t)b * S2 + sh * 64 + ss) * 259 + cb + cc];
    }
    __syncthreads();
    for (int cc = 0; cc < len; cc++) {
      float wv = s_wt[cc][o];
#pragma unroll
      for (int j = 0; j < 16; j++)
        acc[j] = fmaf(wv, s_a[sq * 16 + j][cc], acc[j]);
    }
    __syncthreads();
  }
#pragma unroll
  for (int j = 0; j < 16; j++) {
    int s = sh * 64 + sq * 16 + j;
    h3[((size_t)b * S2 + s) * 512 + ot * 64 + o] = fmaxf(acc[j], 0.f);
  }
}

// ---------------------------------------------------------------------------
// Final MLP layer b + global max-pool over the 128 proposals.
// ---------------------------------------------------------------------------
__global__ __launch_bounds__(256) void mlp3b_kernel(
    const float* __restrict__ h3, const float* __restrict__ W3b,
    const float* __restrict__ b3b, float* __restrict__ out) {
  __shared__ float s_wt[64][65];
  __shared__ float s_h[128][64];
  __shared__ float s_red[4][64];
  int blk = blockIdx.x;
  int b = blk >> 4, ot = blk & 15;
  int tid = threadIdx.x;
  int o = tid & 63, sq = tid >> 6;
  float acc[32];
  float bias = b3b[ot * 64 + o];
#pragma unroll
  for (int j = 0; j < 32; j++) acc[j] = bias;
  for (int ch = 0; ch < 8; ch++) {
    int cb = ch * 64;
    for (int e = tid; e < 4096; e += 256) {
      int oo = e >> 6, cc = e & 63;
      s_wt[cc][oo] = W3b[(size_t)(ot * 64 + oo) * 512 + cb + cc];
    }
    for (int e = tid; e < 8192; e += 256) {
      int ss = e >> 6, cc = e & 63;
      s_h[ss][cc] = h3[((size_t)b * S2 + ss) * 512 + cb + cc];
    }
    __syncthreads();
    for (int c4 = 0; c4 < 16; c4++) {
      float w0 = s_wt[c4 * 4 + 0][o];
      float w1 = s_wt[c4 * 4 + 1][o];
      float w2 = s_wt[c4 * 4 + 2][o];
      float w3 = s_wt[c4 * 4 + 3][o];
#pragma unroll
      for (int j = 0; j < 32; j++) {
        float4 h = *(const float4*)(&s_h[sq * 32 + j][c4 * 4]);
        acc[j] = fmaf(h.x, w0, acc[j]);
        acc[j] = fmaf(h.y, w1, acc[j]);
        acc[j] = fmaf(h.z, w2, acc[j]);
        acc[j] = fmaf(h.w, w3, acc[j]);
      }
    }
    __syncthreads();
  }
  float m = -1e30f;
#pragma unroll
  for (int j = 0; j < 32; j++) m = fmaxf(m, acc[j]);
  s_red[sq][o] = m;
  __syncthreads();
  if (sq == 0) {
    m = fmaxf(fmaxf(s_red[0][o], s_red[1][o]), fmaxf(s_red[2][o], s_red[3][o]));
    out[(size_t)b * 1024 + ot * 64 + o] = fmaxf(m, 0.f);
  }
}

extern "C" void kernel_launch(void* const* d_in, const int* in_sizes, int n_in,
                              void* d_out, int out_size, void* d_ws, size_t ws_size,
                              hipStream_t stream) {
  const float* x = (const float*)d_in[0];
  const float* W1a = (const float*)d_in[1];
  const float* b1a = (const float*)d_in[2];
  const float* W1b = (const float*)d_in[3];
  const float* b1b = (const float*)d_in[4];
  const float* W2a = (const float*)d_in[5];
  const float* b2a = (const float*)d_in[6];
  const float* W2b = (const float*)d_in[7];
  const float* b2b = (const float*)d_in[8];
  const float* W3a = (const float*)d_in[9];
  const float* b3a = (const float*)d_in[10];
  const float* W3b = (const float*)d_in[11];
  const float* b3b = (const float*)d_in[12];
  float* out = (float*)d_out;

  // workspace carve (floats/ints; all segments 16B-aligned) — ~13.3 MB total
  float* nx1 = (float*)d_ws;                       // [16,512,3]
  int* idx1 = (int*)(nx1 + 16 * 512 * 3);          // [16,512,64]
  float* feat1 = (float*)(idx1 + 16 * 512 * 64);   // [16,512,128]
  float* nx2 = feat1 + 16 * 512 * 128;             // [16,128,3]
  int* idx2 = (int*)(nx2 + 16 * 128 * 3);          // [16,128,64]
  float* in3 = (float*)(idx2 + 16 * 128 * 64);     // [16,128,259] = [xyz2|feat2]
  float* h3 = in3 + 16 * 128 * 259;                // [16,128,512]

  fps1_kernel<<<B, 1024, 0, stream>>>(x, nx1, nullptr, 0, N, S1);
  ballq_kernel<<<(B * S1) / 4, 256, 0, stream>>>(x, nx1, idx1, N, S1, B * S1, 0.04f);
  sa1_kernel<<<B * S1, 256, 0, stream>>>(x, idx1, nx1, W1a, b1a, W1b, b1b, feat1);
  fps_wave_kernel<8, 128, 512><<<B, 64, 0, stream>>>(nx1, nx2, in3, 259, S1, S2);
  ballq_kernel<<<(B * S2) / 4, 256, 0, stream>>>(nx1, nx2, idx2, S1, S2, B * S2, 0.16f);
  sa2_kernel<<<B * S2, 256, 0, stream>>>(nx1, feat1, idx2, nx2, W2a, b2a, W2b, b2b, in3);
  mlp3a_kernel<<<256, 256, 0, stream>>>(in3, W3a, b3a, h3);
  mlp3b_kernel<<<256, 256, 0, stream>>>(h3, W3b, b3b, out);
}